// Round 8
// baseline (246.450 us; speedup 1.0000x reference)
//
#include <hip/hip_runtime.h>

// IF (integrate-and-fire) SNN forward scan.
// x: [T*B, C, H, W] fp32 viewed as [T=8, slice=4,194,304 floats]; out same shape.
// Per element n: mem=0.5*thr; for t: mem+=x[t][n]; sp=(mem>=thr)?thr:0; mem-=sp.
//
// R1-R7 history: every register-direct variant (one-shot / persistent /
// SW-pipelined / forced-8-deep-MLP via sched_barrier) lands at 77-85 us
// (~3.4 TB/s eff). R7 falsified the per-wave-MLP theory. Remaining theory:
// the 16 strided streams (16 MiB apart, identical low address bits per
// thread) hotspot one DRAM channel per wave-op and thrash UTCL1 (every op a
// different page). Fill/copy kernels that hit 6.3-6.7 TB/s walk contiguous
// streams.
// R8: block-level LDS staging. Each block DMAs 8 KiB CONTIGUOUS per slice
// (64 KiB total) via global_load_lds width=16 (no VGPR dests, vmcnt-deep MLP,
// contiguous per-wave walk -> channel spread, 1 page/stream/block). Scan
// reads LDS columns, nt-stores coalesced. 2 blocks/CU co-resident hide the
// vmcnt(0)+barrier drain.

typedef float f4 __attribute__((ext_vector_type(4)));

constexpr int T_STEPS = 8;
constexpr int BLOCK   = 256;                  // 4 waves
constexpr int R       = 512;                  // float4 per slice per block (8 KiB)
constexpr int LDS_F4  = T_STEPS * R;          // 4096 f4 = 64 KiB

__global__ __launch_bounds__(BLOCK, 2) void if_fwd_kernel(
    const f4* __restrict__ x,
    const float* __restrict__ thresh,
    f4* __restrict__ out,
    int stride4)   // float4s per timestep slice (1,048,576)
{
    __shared__ f4 lds[LDS_F4];

    const int tid  = threadIdx.x;
    const int base = blockIdx.x * R;           // block's f4 offset within a slice

    const float thr = thresh[0];               // wave-uniform -> scalar load
    const float h   = 0.5f * thr;

    // ---- Stage: 16 async DMA issues/thread, 4 KiB per block-instruction.
    // Issue j covers LDS bytes [j*4KiB, (j+1)*4KiB): slice t = j>>1,
    // r = (j&1)*256 + tid. Per (wave, j) LDS addr = uniform base + lane*16. ✓
#pragma unroll
    for (int j = 0; j < 16; ++j) {
        const int t = j >> 1;
        const int r = ((j & 1) << 8) + tid;
        const f4* src = x + (size_t)t * stride4 + base + r;
        f4* dst = lds + t * R + r;
        __builtin_amdgcn_global_load_lds(
            (const __attribute__((address_space(1))) unsigned int*)src,
            (__attribute__((address_space(3))) unsigned int*)dst,
            16 /*bytes*/, 0 /*offset*/, 0 /*aux*/);
    }
    __builtin_amdgcn_s_waitcnt(0);   // drain vmcnt (global_load_lds completion)
    __syncthreads();

    // ---- Scan + store: each thread handles r = tid and tid+256.
#pragma unroll
    for (int half = 0; half < 2; ++half) {
        const int r = (half << 8) + tid;
        f4 m = {h, h, h, h};
#pragma unroll
        for (int t = 0; t < T_STEPS; ++t) {
            f4 v = lds[t * R + r];             // ds_read_b128, conflict-free
            m += v;
            f4 s;
#pragma unroll
            for (int k = 0; k < 4; ++k) {
                s[k] = (m[k] >= thr) ? thr : 0.0f;
            }
            m -= s;
            __builtin_nontemporal_store(s, out + (size_t)t * stride4 + base + r);
        }
    }
}

extern "C" void kernel_launch(void* const* d_in, const int* in_sizes, int n_in,
                              void* d_out, int out_size, void* d_ws, size_t ws_size,
                              hipStream_t stream) {
    const float* x      = (const float*)d_in[0];   // [T*B, C, H, W] fp32
    const float* thresh = (const float*)d_in[1];   // scalar threshold (1 elem)
    float* out          = (float*)d_out;

    const int total   = in_sizes[0];       // 33,554,432
    const int stride  = total / T_STEPS;   // 4,194,304 elems per slice
    const int stride4 = stride / 4;        // 1,048,576 float4s per slice

    dim3 block(BLOCK);
    dim3 grid(stride4 / R);                // 2048 blocks, one tile each
    if_fwd_kernel<<<grid, block, 0, stream>>>(
        (const f4*)x, thresh, (f4*)out, stride4);
}

// Round 9
// 222.829 us; speedup vs baseline: 1.1060x; 1.1060x over previous
//
#include <hip/hip_runtime.h>

// IF (integrate-and-fire) SNN forward scan.
// x: [T*B, C, H, W] fp32 viewed as [T=8, slice=4,194,304 floats]; out same shape.
// Per element n: mem=0.5*thr; for t: mem+=x[t][n]; sp=(mem>=thr)?thr:0; mem-=sp.
//
// R1: one-shot f4, normal ld/st        -> 90 us   (VGPR 28)
// R2: one-shot ILP=2 + nt st           -> 83 us   (VGPR 32 -> 16 dests impossible,
//                                                  loads serialized by recycling)
// R3: persistent + nt ld + nt st       -> <80 us  (best; invisible in top-5)
// R4: R3 w/ normal loads               -> 100 us  (nt LOADS are a real +25%;
//                                                  FETCH identical -> L1/miss-path,
//                                                  not traffic)
// R5: + SW pipeline                    -> ~R3     (VGPR stuck at 32, flattened)
// R6: + launch_bounds(256,4)           -> unobservable
// R7: one-shot + sched_barrier forced 8-deep MLP -> ~R3 (agg 232.5, best)
// R8: LDS staging via global_load_lds  -> 90-95 us REGRESSED (occupancy 17%,
//     serial stage->barrier->store phases; stream-contiguity theory dead)
//
// R9 (last orthogonal lever): forced 16-deep MLP. R2's ILP=2 never actually
// ran with 16 live dests (VGPR=32). launch_bounds(256,3) (~168 VGPR budget) +
// sched_barrier(0) forces 16 distinct float4 dests = 4 KiB outstanding
// reads/thread, 2 KiB within-stream bursts. If neutral -> the limiter is the
// 16-stream strided pattern at DRAM (8 row-streams/bank vs copy's 1) and
// ~78 us is the practical roofline for this layout.

typedef float f4 __attribute__((ext_vector_type(4)));

constexpr int T_STEPS = 8;
constexpr int BLOCK   = 256;
constexpr int ILP     = 2;      // two n-columns per thread

__global__ __launch_bounds__(BLOCK, 3) void if_fwd_kernel(
    const f4* __restrict__ x,
    const float* __restrict__ thresh,
    f4* __restrict__ out,
    int stride4)   // float4s per timestep slice (1,048,576)
{
    const int i0 = blockIdx.x * (BLOCK * ILP) + threadIdx.x;

    const float thr = thresh[0];      // wave-uniform -> scalar load
    const float h   = 0.5f * thr;

    // 16 independent nt loads; sched_barrier(0) forbids sinking any past it,
    // so all 16 must be in flight with distinct dest VGPRs (64 VGPRs of data).
    f4 xt[T_STEPS][ILP];
#pragma unroll
    for (int t = 0; t < T_STEPS; ++t) {
#pragma unroll
        for (int j = 0; j < ILP; ++j) {
            xt[t][j] = __builtin_nontemporal_load(
                x + (size_t)t * stride4 + i0 + j * BLOCK);
        }
    }
    __builtin_amdgcn_sched_barrier(0);

    f4 m[ILP];
#pragma unroll
    for (int j = 0; j < ILP; ++j) {
        m[j] = (f4){h, h, h, h};
    }

#pragma unroll
    for (int t = 0; t < T_STEPS; ++t) {
#pragma unroll
        for (int j = 0; j < ILP; ++j) {
            m[j] += xt[t][j];
            f4 s;
#pragma unroll
            for (int k = 0; k < 4; ++k) {
                s[k] = (m[j][k] >= thr) ? thr : 0.0f;
            }
            m[j] -= s;
            __builtin_nontemporal_store(
                s, out + (size_t)t * stride4 + i0 + j * BLOCK);
        }
    }
}

extern "C" void kernel_launch(void* const* d_in, const int* in_sizes, int n_in,
                              void* d_out, int out_size, void* d_ws, size_t ws_size,
                              hipStream_t stream) {
    const float* x      = (const float*)d_in[0];   // [T*B, C, H, W] fp32
    const float* thresh = (const float*)d_in[1];   // scalar threshold (1 elem)
    float* out          = (float*)d_out;

    const int total   = in_sizes[0];       // 33,554,432
    const int stride  = total / T_STEPS;   // 4,194,304 elems per slice
    const int stride4 = stride / 4;        // 1,048,576 float4s per slice

    dim3 block(BLOCK);
    dim3 grid(stride4 / (BLOCK * ILP));    // 2048 blocks, one-shot
    if_fwd_kernel<<<grid, block, 0, stream>>>(
        (const f4*)x, thresh, (f4*)out, stride4);
}

// Round 10
// 217.848 us; speedup vs baseline: 1.1313x; 1.0229x over previous
//
#include <hip/hip_runtime.h>

// IF (integrate-and-fire) SNN forward scan.
// x: [T*B, C, H, W] fp32 viewed as [T=8, slice=4,194,304 floats]; out same shape.
// Per element n: mem=0.5*thr; for t: mem+=x[t][n]; sp=(mem>=thr)?thr:0; mem-=sp.
//
// Ladder (aggregate bench us; kernel est = agg - ~155 overhead):
// R1  one-shot f4, normal ld/st            -> agg 243.8 (kernel 90)
// R2  one-shot ILP=2 + nt st (VGPR 32!)    -> agg 233.8 (kernel 83)
// R3  persistent + nt ld + nt st           -> agg 238.9 (kernel <80)
// R4  R3 w/ normal loads                   -> agg 258.6 (kernel 100; nt ld = +25%)
// R5  + SW pipeline (flattened, VGPR 32)   -> agg 235.6
// R7  forced  8-deep MLP (sched_barrier)   -> agg 232.5
// R8  LDS staging (global_load_lds)        -> agg 246.5 REGRESSED
// R9  forced 16-deep MLP (ILP=2, lb(256,3))-> agg 222.8 BEST (-10, real)
//
// CONCLUSION: limiter = per-wave outstanding read bytes MATERIALIZED in
// distinct dest VGPRs. Default VGPR=32 budget silently serialized every
// earlier variant. Depth 8->16 paid -10 us. R10 rides the gradient: 32-deep.
//
// R10: ILP=4, 32 pinned nt loads (128 VGPRs data), launch_bounds(256,2)
// (256-VGPR budget). One-shot 1024 blocks. If neutral vs R9 -> depth
// saturated; remaining gap to 43-us copy-roofline is pattern-intrinsic.

typedef float f4 __attribute__((ext_vector_type(4)));

constexpr int T_STEPS = 8;
constexpr int BLOCK   = 256;
constexpr int ILP     = 4;      // four n-columns per thread

__global__ __launch_bounds__(BLOCK, 2) void if_fwd_kernel(
    const f4* __restrict__ x,
    const float* __restrict__ thresh,
    f4* __restrict__ out,
    int stride4)   // float4s per timestep slice (1,048,576)
{
    const int i0 = blockIdx.x * (BLOCK * ILP) + threadIdx.x;

    const float thr = thresh[0];      // wave-uniform -> scalar load
    const float h   = 0.5f * thr;

    // 32 independent nt loads; sched_barrier(0) pins them all before any
    // consumption -> 32 distinct f4 dests (128 VGPRs), 8 KiB in flight/thread.
    f4 xt[T_STEPS][ILP];
#pragma unroll
    for (int t = 0; t < T_STEPS; ++t) {
#pragma unroll
        for (int j = 0; j < ILP; ++j) {
            xt[t][j] = __builtin_nontemporal_load(
                x + (size_t)t * stride4 + i0 + j * BLOCK);
        }
    }
    __builtin_amdgcn_sched_barrier(0);

    f4 m[ILP];
#pragma unroll
    for (int j = 0; j < ILP; ++j) {
        m[j] = (f4){h, h, h, h};
    }

#pragma unroll
    for (int t = 0; t < T_STEPS; ++t) {
#pragma unroll
        for (int j = 0; j < ILP; ++j) {
            m[j] += xt[t][j];
            f4 s;
#pragma unroll
            for (int k = 0; k < 4; ++k) {
                s[k] = (m[j][k] >= thr) ? thr : 0.0f;
            }
            m[j] -= s;
            __builtin_nontemporal_store(
                s, out + (size_t)t * stride4 + i0 + j * BLOCK);
        }
    }
}

extern "C" void kernel_launch(void* const* d_in, const int* in_sizes, int n_in,
                              void* d_out, int out_size, void* d_ws, size_t ws_size,
                              hipStream_t stream) {
    const float* x      = (const float*)d_in[0];   // [T*B, C, H, W] fp32
    const float* thresh = (const float*)d_in[1];   // scalar threshold (1 elem)
    float* out          = (float*)d_out;

    const int total   = in_sizes[0];       // 33,554,432
    const int stride  = total / T_STEPS;   // 4,194,304 elems per slice
    const int stride4 = stride / 4;        // 1,048,576 float4s per slice

    dim3 block(BLOCK);
    dim3 grid(stride4 / (BLOCK * ILP));    // 1024 blocks, one-shot
    if_fwd_kernel<<<grid, block, 0, stream>>>(
        (const f4*)x, thresh, (f4*)out, stride4);
}